// Round 8
// baseline (168.134 us; speedup 1.0000x reference)
//
#include <hip/hip_runtime.h>
#include <hip/hip_cooperative_groups.h>

#define NMOL   32
#define NATOM  512
#define NPAIR  32768
#define NB     64
#define HIDDEN 256
#define TOTNATOM (NMOL * NATOM)
#define NSUB   8
#define CAP2   64    // in-cutoff records/atom: mean ~19, max ~40 observed-safe

// ---------------------------------------------------------------------------
// K0: zero cnt + dipole (stream-ordered before the fused kernel)
// ---------------------------------------------------------------------------
__global__ __launch_bounds__(256) void zero_kernel(unsigned* __restrict__ cnt,
                                                   float* __restrict__ dipole, int ndip)
{
    const int i = blockIdx.x * 256 + threadIdx.x;
    if (i < TOTNATOM) cnt[i] = 0u;
    if (i < ndip) dipole[i] = 0.f;
}

// ---------------------------------------------------------------------------
// Fused cooperative kernel: 256 blocks x 1024 threads (1 block/CU).
//   phase 1 scatter: block = (mol, sub) pair slice -> rec buckets + LDS tv
//   grid.sync()
//   phase 2 gather: block owns atoms [64b, 64b+64): density -> LDS (never
//                   leaves the CU), tv = sum of 8 block partials
//   __syncthreads()
//   phase 3 nn:     64->256 silu MLP from LDS density, dipole atomics
// Single dispatch => dur_us/counters attribute cleanly (R7's profile was
// blacked out by 40us harness poison fills hiding all 4 sub-kernels).
// ---------------------------------------------------------------------------
__global__ __launch_bounds__(1024) void fused_kernel(
    const float* __restrict__ cart, const float* __restrict__ shifts,
    const float* __restrict__ centers, const float* __restrict__ widths,
    const float* __restrict__ c_emb, const int* __restrict__ species,
    const int* __restrict__ atom_index,
    const float* __restrict__ W1, const float* __restrict__ b1,
    const float* __restrict__ W2, const float* __restrict__ b2,
    unsigned* __restrict__ cnt, float2* __restrict__ rec,
    float* __restrict__ tv_part, float* __restrict__ dipole)
{
    __shared__ float tv_sc[NATOM * 3];     // 6 KB  scatter-phase per-mol tv
    __shared__ float cemb[8 * NB];         // 2 KB
    __shared__ float dens_l[64 * NB];      // 16 KB gather output (block's atoms)
    __shared__ float tv_l[64 * 3];         // 768 B
    __shared__ float part_l[4][4][16];     // 1 KB  nn wave partials

    const int tid = threadIdx.x;
    const int b   = blockIdx.x;
    const int mol = b >> 3;
    const int sub = b & 7;

    for (int i = tid; i < NATOM * 3; i += 1024) tv_sc[i] = 0.f;
    if (tid < 8 * NB) cemb[tid] = c_emb[tid];
    __syncthreads();

    // ---------------- phase 1: scatter ----------------
    {
        const int*   ai0 = atom_index + (size_t)mol * NPAIR;
        const int*   ai1 = ai0 + (size_t)NMOL * NPAIR;
        const float* sh  = shifts + (size_t)mol * NPAIR * 3;
        const float* cm  = cart + (size_t)mol * NATOM * 3;
        const int*   sp  = species + (size_t)mol * NATOM;
        const int base = sub * 4096;

        for (int k = 0; k < 4; ++k) {
            const int p  = base + k * 1024 + tid;
            const int i0 = ai0[p];
            const int i1 = ai1[p];
            const float sx = sh[p * 3 + 0], sy = sh[p * 3 + 1], sz = sh[p * 3 + 2];
            if (!(sx > -1e10f && sy > -1e10f && sz > -1e10f)) continue;  // masked
            const float dx = cm[i0 * 3 + 0] - cm[i1 * 3 + 0] + sx;
            const float dy = cm[i0 * 3 + 1] - cm[i1 * 3 + 1] + sy;
            const float dz = cm[i0 * 3 + 2] - cm[i1 * 3 + 2] + sz;
            unsafeAtomicAdd(&tv_sc[i0 * 3 + 0], dx);    // ds_add_f32
            unsafeAtomicAdd(&tv_sc[i0 * 3 + 1], dy);
            unsafeAtomicAdd(&tv_sc[i0 * 3 + 2], dz);
            const float d = sqrtf(dx * dx + dy * dy + dz * dz + 1e-12f);
            if (d < 5.0f) {
                const float fc = 0.5f * (__cosf(0.62831853071795864769f * d) + 1.f);
                // pack spc into fc's low 3 mantissa bits (<=2^-20 rel perturbation)
                const unsigned fb = (__float_as_uint(fc) & ~7u) | (unsigned)sp[i1];
                const int ga = mol * NATOM + i0;
                const unsigned pos = atomicAdd(&cnt[ga], 1u);   // device-scope
                if (pos < CAP2)
                    rec[(size_t)ga * CAP2 + pos] = make_float2(d, __uint_as_float(fb));
            }
        }
        __syncthreads();
        float* tg = tv_part + (size_t)b * NATOM * 3;
        for (int i = tid; i < NATOM * 3; i += 1024) tg[i] = tv_sc[i];
    }

    __threadfence();                                   // release rec/tv_part
    cooperative_groups::this_grid().sync();            // cross-XCD barrier

    // ---------------- phase 2: gather ----------------
    {
        const int lane = tid & 63;
        const int wave = tid >> 6;
        const float cb  = centers[lane];
        const float nwb = -widths[lane];

        for (int al = wave; al < 64; al += 16) {       // 4 atoms per wave
            const int a = b * 64 + al;                 // global atom
            const int n = min((int)cnt[a], CAP2);
            const float2* r = rec + (size_t)a * CAP2;
            float acc = 0.f;
            int k = 0;
            for (; k + 2 <= n; k += 2) {               // 2 independent chains
                const float2 r0 = r[k], r1 = r[k + 1];
                const unsigned f0 = __float_as_uint(r0.y), f1 = __float_as_uint(r1.y);
                const float t0 = r0.x - cb, t1 = r1.x - cb;
                acc = fmaf(__expf(nwb * t0 * t0) * __uint_as_float(f0 & ~7u),
                           cemb[((f0 & 7u) << 6) | lane], acc);
                acc = fmaf(__expf(nwb * t1 * t1) * __uint_as_float(f1 & ~7u),
                           cemb[((f1 & 7u) << 6) | lane], acc);
            }
            if (k < n) {
                const float2 r0 = r[k];
                const unsigned f0 = __float_as_uint(r0.y);
                const float t0 = r0.x - cb;
                acc = fmaf(__expf(nwb * t0 * t0) * __uint_as_float(f0 & ~7u),
                           cemb[((f0 & 7u) << 6) | lane], acc);
            }
            dens_l[al * NB + lane] = acc;

            if (lane < 3) {                            // sum 8 tv block-partials
                const int ra = (sub << 6) + al;        // within-mol atom index
                float s = 0.f;
#pragma unroll
                for (int sb = 0; sb < NSUB; ++sb)
                    s += tv_part[((size_t)(mol * NSUB + sb) * NATOM + ra) * 3 + lane];
                tv_l[al * 3 + lane] = s;
            }
        }
    }
    __syncthreads();

    // ---------------- phase 3: nn ----------------
    {
        const int j  = tid & 255;                      // hidden unit
        const int g  = tid >> 8;                       // atom group (16 atoms)
        const int wg = (tid >> 6) & 3;                 // wave within group

        float w1r[64];
#pragma unroll
        for (int q = 0; q < 64; ++q) w1r[q] = W1[q * HIDDEN + j];
        const float b1v = b1[j];
        const float w2v = W2[j];

#pragma unroll
        for (int a = 0; a < 16; ++a) {
            const float* row = &dens_l[(g * 16 + a) * NB];   // wave-uniform -> LDS broadcast
            float h0 = b1v, h1 = 0.f, h2 = 0.f, h3 = 0.f;
#pragma unroll
            for (int q = 0; q < 64; q += 4) {
                h0 = fmaf(row[q + 0], w1r[q + 0], h0);
                h1 = fmaf(row[q + 1], w1r[q + 1], h1);
                h2 = fmaf(row[q + 2], w1r[q + 2], h2);
                h3 = fmaf(row[q + 3], w1r[q + 3], h3);
            }
            const float h = (h0 + h1) + (h2 + h3);
            float con = (h / (1.f + __expf(-h))) * w2v;      // silu * W2
#pragma unroll
            for (int off = 32; off; off >>= 1) con += __shfl_down(con, off);
            if ((tid & 63) == 0) part_l[g][wg][a] = con;
        }
        __syncthreads();

        if (tid < 64) {
            const int a  = tid;                        // local atom
            const int gg = a >> 4, aa = a & 15;
            const float out = part_l[gg][0][aa] + part_l[gg][1][aa]
                            + part_l[gg][2][aa] + part_l[gg][3][aa] + b2[0];
            float px = out * tv_l[a * 3 + 0];
            float py = out * tv_l[a * 3 + 1];
            float pz = out * tv_l[a * 3 + 2];
#pragma unroll
            for (int off = 32; off; off >>= 1) {
                px += __shfl_down(px, off);
                py += __shfl_down(py, off);
                pz += __shfl_down(pz, off);
            }
            if (tid == 0) {
                unsafeAtomicAdd(&dipole[mol * 3 + 0], px);
                unsafeAtomicAdd(&dipole[mol * 3 + 1], py);
                unsafeAtomicAdd(&dipole[mol * 3 + 2], pz);
            }
        }
    }
}

// ---------------------------------------------------------------------------
extern "C" void kernel_launch(void* const* d_in, const int* in_sizes, int n_in,
                              void* d_out, int out_size, void* d_ws, size_t ws_size,
                              hipStream_t stream)
{
    const float* cart       = (const float*)d_in[0];
    const float* shifts     = (const float*)d_in[1];
    const float* centers    = (const float*)d_in[2];
    const float* widths     = (const float*)d_in[3];
    const float* c_emb      = (const float*)d_in[4];
    const float* W1         = (const float*)d_in[5];
    const float* b1         = (const float*)d_in[6];
    const float* W2         = (const float*)d_in[7];
    const float* b2         = (const float*)d_in[8];
    const int*   species    = (const int*)d_in[10];
    const int*   atom_index = (const int*)d_in[11];

    // ws layout: tv_part(1.5MB) | cnt(64KB) | rec(8MB)
    float*    tv_part = (float*)d_ws;
    unsigned* cnt     = (unsigned*)(tv_part + (size_t)NMOL * NSUB * NATOM * 3);
    float2*   rec     = (float2*)(cnt + TOTNATOM);
    float*    dipole  = (float*)d_out;

    hipLaunchKernelGGL(zero_kernel, dim3((TOTNATOM + 255) / 256), dim3(256), 0, stream,
                       cnt, dipole, out_size);

    void* args[] = {
        (void*)&cart, (void*)&shifts, (void*)&centers, (void*)&widths,
        (void*)&c_emb, (void*)&species, (void*)&atom_index,
        (void*)&W1, (void*)&b1, (void*)&W2, (void*)&b2,
        (void*)&cnt, (void*)&rec, (void*)&tv_part, (void*)&dipole
    };
    hipLaunchCooperativeKernel((void*)fused_kernel, dim3(NMOL * NSUB), dim3(1024),
                               args, 0, stream);
}

// Round 9
// 69.880 us; speedup vs baseline: 2.4061x; 2.4061x over previous
//
#include <hip/hip_runtime.h>

#define NMOL   32
#define NATOM  512
#define NPAIR  32768
#define NB     64
#define HIDDEN 256
#define TOTNATOM (NMOL * NATOM)
#define NSUB   8
#define CAP8   16   // records per (atom, sub-block): lambda~2.3, P(>=16)~4e-9

// ---------------------------------------------------------------------------
// K1 scatter: 256 blocks (mol x sub) x 1024 thr, 4 pairs/thread.
// Counters privatized in LDS (native ds_add_rtn_u32) -> per-block record
// segments. ZERO cross-XCD atomics (R7's scatter stalled ~30us on cnt[] line
// ping-pong: 280K device atomics over ~1K lines from 8 XCDs, VALUBusy 1.4%).
// ---------------------------------------------------------------------------
__global__ __launch_bounds__(1024) void scatter_kernel(
    const float* __restrict__ cart, const float* __restrict__ shifts,
    const int* __restrict__ species, const int* __restrict__ atom_index,
    unsigned* __restrict__ cnt8, float2* __restrict__ rec,
    float* __restrict__ tv_part)
{
    __shared__ float    tv_sc[NATOM * 3];   // 6 KB
    __shared__ unsigned lcnt[NATOM];        // 2 KB
    const int tid = threadIdx.x;
    const int b   = blockIdx.x;
    const int mol = b >> 3;
    const int sub = b & 7;

    for (int i = tid; i < NATOM * 3; i += 1024) tv_sc[i] = 0.f;
    if (tid < NATOM) lcnt[tid] = 0u;
    __syncthreads();

    const int*   ai0 = atom_index + (size_t)mol * NPAIR;
    const int*   ai1 = ai0 + (size_t)NMOL * NPAIR;
    const float* sh  = shifts + (size_t)mol * NPAIR * 3;
    const float* cm  = cart + (size_t)mol * NATOM * 3;
    const int*   sp  = species + (size_t)mol * NATOM;
    const int base = sub * 4096;

#pragma unroll
    for (int k = 0; k < 4; ++k) {
        const int p  = base + k * 1024 + tid;
        const int i0 = ai0[p];
        const int i1 = ai1[p];
        const float sx = sh[p * 3 + 0], sy = sh[p * 3 + 1], sz = sh[p * 3 + 2];
        if (!(sx > -1e10f && sy > -1e10f && sz > -1e10f)) continue;  // masked
        const float dx = cm[i0 * 3 + 0] - cm[i1 * 3 + 0] + sx;
        const float dy = cm[i0 * 3 + 1] - cm[i1 * 3 + 1] + sy;
        const float dz = cm[i0 * 3 + 2] - cm[i1 * 3 + 2] + sz;
        unsafeAtomicAdd(&tv_sc[i0 * 3 + 0], dx);        // ds_add_f32
        unsafeAtomicAdd(&tv_sc[i0 * 3 + 1], dy);
        unsafeAtomicAdd(&tv_sc[i0 * 3 + 2], dz);
        const float d = sqrtf(dx * dx + dy * dy + dz * dz + 1e-12f);
        if (d < 5.0f) {
            const float fc = 0.5f * (__cosf(0.62831853071795864769f * d) + 1.f);
            // pack spc into fc's low 3 mantissa bits (<=2^-20 rel perturbation)
            const unsigned fb = (__float_as_uint(fc) & ~7u) | (unsigned)sp[i1];
            const unsigned pos = atomicAdd(&lcnt[i0], 1u);   // LDS, native
            if (pos < CAP8)
                rec[((size_t)b * NATOM + i0) * CAP8 + pos] =
                    make_float2(d, __uint_as_float(fb));
        }
    }
    __syncthreads();

    if (tid < NATOM) cnt8[((size_t)mol * NATOM + tid) * NSUB + sub] = lcnt[tid];
    float* tg = tv_part + (size_t)b * NATOM * 3;
    for (int i = tid; i < NATOM * 3; i += 1024) tg[i] = tv_sc[i];
}

// ---------------------------------------------------------------------------
// K2 gather+nn: 1024 blocks x 256 thr (launch_bounds(256,4): <=128 VGPR so
// w1r[64] stays in registers -- R8's 1024-thr fusion spilled it at VGPR=48).
// Gather: wave = atom (4 per wave seq), lane = basis; density -> 4 KB LDS.
// NN: thread = hidden unit, 16 atoms from LDS; partial dipole per block.
// ---------------------------------------------------------------------------
__global__ __launch_bounds__(256, 4) void gathernn_kernel(
    const unsigned* __restrict__ cnt8, const float2* __restrict__ rec,
    const float* __restrict__ centers, const float* __restrict__ widths,
    const float* __restrict__ c_emb, const float* __restrict__ tv_part,
    const float* __restrict__ W1, const float* __restrict__ b1,
    const float* __restrict__ W2, const float* __restrict__ b2,
    float* __restrict__ dip_part)
{
    __shared__ float cemb[8 * NB];      // 2 KB
    __shared__ float dens_l[16 * NB];   // 4 KB
    __shared__ float tv_l[16 * 3];
    __shared__ float part_l[4][16];

    const int tid  = threadIdx.x;
    const int lane = tid & 63;
    const int wave = tid >> 6;
    const int a0   = blockIdx.x * 16;   // global atom base
    const int mol  = blockIdx.x >> 5;   // 32 blocks per molecule

    for (int i = tid; i < 8 * NB; i += 256) cemb[i] = c_emb[i];
    __syncthreads();

    // ---- gather ----
    {
        const float cb  = centers[lane];
        const float nwb = -widths[lane];
        const uint4* c4 = reinterpret_cast<const uint4*>(cnt8);

        for (int al = wave; al < 16; al += 4) {
            const int a  = a0 + al;
            const int ra = a & 511;
            const uint4 cA = c4[a * 2];        // cnt8[a][0..3]
            const uint4 cB = c4[a * 2 + 1];    // cnt8[a][4..7]
            const unsigned ns[8] = {cA.x, cA.y, cA.z, cA.w, cB.x, cB.y, cB.z, cB.w};
            float acc = 0.f;
#pragma unroll
            for (int s = 0; s < 8; ++s) {
                const int n = min((int)ns[s], CAP8);
                const float2* r = rec + ((size_t)(mol * NSUB + s) * NATOM + ra) * CAP8;
                int k = 0;
                for (; k + 2 <= n; k += 2) {
                    const float2 r0 = r[k], r1 = r[k + 1];
                    const unsigned f0 = __float_as_uint(r0.y), f1 = __float_as_uint(r1.y);
                    const float t0 = r0.x - cb, t1 = r1.x - cb;
                    acc = fmaf(__expf(nwb * t0 * t0) * __uint_as_float(f0 & ~7u),
                               cemb[((f0 & 7u) << 6) | lane], acc);
                    acc = fmaf(__expf(nwb * t1 * t1) * __uint_as_float(f1 & ~7u),
                               cemb[((f1 & 7u) << 6) | lane], acc);
                }
                if (k < n) {
                    const float2 r0 = r[k];
                    const unsigned f0 = __float_as_uint(r0.y);
                    const float t0 = r0.x - cb;
                    acc = fmaf(__expf(nwb * t0 * t0) * __uint_as_float(f0 & ~7u),
                               cemb[((f0 & 7u) << 6) | lane], acc);
                }
            }
            dens_l[al * NB + lane] = acc;

            if (lane < 3) {                    // sum the 8 tv block-partials
                float s = 0.f;
#pragma unroll
                for (int sb = 0; sb < NSUB; ++sb)
                    s += tv_part[((size_t)(mol * NSUB + sb) * NATOM + ra) * 3 + lane];
                tv_l[al * 3 + lane] = s;
            }
        }
    }
    __syncthreads();

    // ---- nn ----
    {
        const int j = tid;                     // hidden unit 0..255
        float w1r[64];
#pragma unroll
        for (int q = 0; q < 64; ++q) w1r[q] = W1[q * HIDDEN + j];
        const float b1v = b1[j];
        const float w2v = W2[j];

#pragma unroll
        for (int a = 0; a < 16; ++a) {
            const float* row = &dens_l[a * NB];     // wave-uniform LDS broadcast
            float h0 = b1v, h1 = 0.f, h2 = 0.f, h3 = 0.f;
#pragma unroll
            for (int q = 0; q < 64; q += 4) {
                h0 = fmaf(row[q + 0], w1r[q + 0], h0);
                h1 = fmaf(row[q + 1], w1r[q + 1], h1);
                h2 = fmaf(row[q + 2], w1r[q + 2], h2);
                h3 = fmaf(row[q + 3], w1r[q + 3], h3);
            }
            const float h = (h0 + h1) + (h2 + h3);
            float con = (h / (1.f + __expf(-h))) * w2v;   // silu * W2
#pragma unroll
            for (int off = 32; off; off >>= 1) con += __shfl_down(con, off);
            if (lane == 0) part_l[wave][a] = con;
        }
        __syncthreads();

        if (tid < 16) {
            const int a = tid;
            const float out = part_l[0][a] + part_l[1][a]
                            + part_l[2][a] + part_l[3][a] + b2[0];
            float px = out * tv_l[a * 3 + 0];
            float py = out * tv_l[a * 3 + 1];
            float pz = out * tv_l[a * 3 + 2];
#pragma unroll
            for (int off = 8; off; off >>= 1) {
                px += __shfl_down(px, off, 16);
                py += __shfl_down(py, off, 16);
                pz += __shfl_down(pz, off, 16);
            }
            if (a == 0) {
                dip_part[blockIdx.x * 3 + 0] = px;   // plain store, no atomics
                dip_part[blockIdx.x * 3 + 1] = py;
                dip_part[blockIdx.x * 3 + 2] = pz;
            }
        }
    }
}

// ---------------------------------------------------------------------------
// K3 dipfinal: one tiny block reduces 32 partials per molecule.
// ---------------------------------------------------------------------------
__global__ __launch_bounds__(128) void dipfinal_kernel(
    const float* __restrict__ dip_part, float* __restrict__ dipole)
{
    const int t = threadIdx.x;
    if (t < NMOL * 3) {
        const int m = t / 3, c = t - m * 3;
        float s = 0.f;
#pragma unroll
        for (int k = 0; k < 32; ++k) s += dip_part[(m * 32 + k) * 3 + c];
        dipole[t] = s;
    }
}

// ---------------------------------------------------------------------------
extern "C" void kernel_launch(void* const* d_in, const int* in_sizes, int n_in,
                              void* d_out, int out_size, void* d_ws, size_t ws_size,
                              hipStream_t stream)
{
    const float* cart       = (const float*)d_in[0];
    const float* shifts     = (const float*)d_in[1];
    const float* centers    = (const float*)d_in[2];
    const float* widths     = (const float*)d_in[3];
    const float* c_emb      = (const float*)d_in[4];
    const float* W1         = (const float*)d_in[5];
    const float* b1         = (const float*)d_in[6];
    const float* W2         = (const float*)d_in[7];
    const float* b2         = (const float*)d_in[8];
    const int*   species    = (const int*)d_in[10];
    const int*   atom_index = (const int*)d_in[11];

    // ws: tv_part(1.5MB) | cnt8(512KB) | dip_part(12KB) | rec(16MB)
    float*    tv_part  = (float*)d_ws;
    unsigned* cnt8     = (unsigned*)(tv_part + (size_t)NMOL * NSUB * NATOM * 3);
    float*    dip_part = (float*)(cnt8 + (size_t)TOTNATOM * NSUB);
    float2*   rec      = (float2*)(dip_part + (size_t)(TOTNATOM / 16) * 3);
    float*    dipole   = (float*)d_out;

    hipLaunchKernelGGL(scatter_kernel, dim3(NMOL * NSUB), dim3(1024), 0, stream,
                       cart, shifts, species, atom_index, cnt8, rec, tv_part);
    hipLaunchKernelGGL(gathernn_kernel, dim3(TOTNATOM / 16), dim3(256), 0, stream,
                       cnt8, rec, centers, widths, c_emb, tv_part,
                       W1, b1, W2, b2, dip_part);
    hipLaunchKernelGGL(dipfinal_kernel, dim3(1), dim3(128), 0, stream,
                       dip_part, dipole);
}